// Round 4
// baseline (1164.851 us; speedup 1.0000x reference)
//
#include <hip/hip_runtime.h>

// GIN: 2x GINConv(eps=0), N=50000, E=800000, d=128. bf16 + MFMA.
// R4: CSR eliminated. One LDS-staged bucket-binning pass (dst/49 -> 1021
// buckets), then per-bucket gather with LDS f32 accumulators (direct ds_add
// scatter). Kills fill_kernel's 52MB false-sharing writeback + hist/scan/memcpy.
// ws: [ xb 12.8M | zb 12.8M | tb 12.8M | wt 128K | gcnt 4K | ebuf 5.2M ]

#define NN 50000
#define NE 800000
#define FD 128
#define BNODES 49
#define NB 1021          // ceil(NN/49); bucket 1020 has 20 nodes
#define BCAP 1280        // max edges/bucket: mean 784, sigma 28 -> +17 sigma
#define EPW 4096
#define NWG_BIN 196      // ceil(NE/EPW)

typedef unsigned short u16;
typedef unsigned int u32;
typedef __attribute__((ext_vector_type(8))) short bf16x8;
typedef __attribute__((ext_vector_type(4))) float f32x4;

static __device__ __forceinline__ float b2f(u16 u) {
    return __uint_as_float(((u32)u) << 16);
}
static __device__ __forceinline__ u16 f2b(float f) {
    u32 x = __float_as_uint(f);
    u32 r = x + 0x7FFFu + ((x >> 16) & 1u);   // RNE
    return (u16)(r >> 16);
}

// ---------------- converts ----------------

__global__ __launch_bounds__(256) void convert_x_kernel(
    const float* __restrict__ x, u16* __restrict__ xb)
{
    int gid = blockIdx.x * 256 + threadIdx.x;
    size_t base = (size_t)gid * 8;
    float4 a = *reinterpret_cast<const float4*>(x + base);
    float4 b = *reinterpret_cast<const float4*>(x + base + 4);
    u32 w0 = (u32)f2b(a.x) | ((u32)f2b(a.y) << 16);
    u32 w1 = (u32)f2b(a.z) | ((u32)f2b(a.w) << 16);
    u32 w2 = (u32)f2b(b.x) | ((u32)f2b(b.y) << 16);
    u32 w3 = (u32)f2b(b.z) | ((u32)f2b(b.w) << 16);
    uint4 o = {w0, w1, w2, w3};
    *reinterpret_cast<uint4*>(xb + base) = o;
}

// W [128][128] fp32 row-major -> WT[n][k] = W[k][n] bf16
__global__ __launch_bounds__(256) void convert_w_kernel(
    const float* __restrict__ w0, const float* __restrict__ w1,
    const float* __restrict__ w2, const float* __restrict__ w3,
    u16* __restrict__ wt)
{
    int b = blockIdx.x;
    const float* W = (b == 0) ? w0 : (b == 1) ? w1 : (b == 2) ? w2 : w3;
    u16* out = wt + (size_t)b * FD * FD;
    for (int idx = threadIdx.x; idx < FD * FD; idx += 256) {
        int n = idx >> 7, k = idx & 127;
        out[idx] = f2b(W[k * FD + n]);
    }
}

// ---------------- bucket binning (replaces CSR build) ----------------
// Edges grouped by bucket b = dst/49 into ebuf[b*BCAP ...], packed
// u32 = src | (dst_local << 16). Order within bucket is irrelevant.

__global__ __launch_bounds__(256) void bin_kernel(
    const int* __restrict__ ei, u32* __restrict__ ebuf, int* __restrict__ gcnt)
{
    __shared__ int cnt[1024];
    __shared__ int lofs[1024];
    __shared__ int cur[1024];
    __shared__ int gb[1024];
    __shared__ int csum[16];
    __shared__ int cofs[16];
    __shared__ u32 vals[EPW];
    __shared__ u16 bkt[EPW];

    const int tid = threadIdx.x, lane = tid & 63, wv = tid >> 6;
    const int e0 = blockIdx.x * EPW;
    const int nE = min(EPW, NE - e0);
    const int* dstp = ei + NE;

    for (int i = tid; i < 1024; i += 256) { cnt[i] = 0; cur[i] = 0; }
    __syncthreads();

    // count
    for (int k = 0; k < EPW / 256; ++k) {
        int e = e0 + k * 256 + tid;
        if (e < NE) atomicAdd(&cnt[(u32)dstp[e] / BNODES], 1);
    }
    __syncthreads();

    // exclusive scan over 1024 slots (16 chunks of 64)
    for (int cc = 0; cc < 4; ++cc) {
        int c = wv + cc * 4;
        int i = c * 64 + lane;
        int v = cnt[i];
        int sc = v;
#pragma unroll
        for (int s = 1; s < 64; s <<= 1) {
            int t = __shfl_up(sc, s);
            if (lane >= s) sc += t;
        }
        lofs[i] = sc - v;
        if (lane == 63) csum[c] = sc;
    }
    __syncthreads();
    if (wv == 0) {
        int s = (lane < 16) ? csum[lane] : 0;
        int sc = s;
#pragma unroll
        for (int st = 1; st < 16; st <<= 1) {
            int t = __shfl_up(sc, st);
            if (lane >= st) sc += t;
        }
        if (lane < 16) cofs[lane] = sc - s;
    }
    __syncthreads();
    for (int cc = 0; cc < 4; ++cc) {
        int c = wv + cc * 4;
        lofs[c * 64 + lane] += cofs[c];
    }
    __syncthreads();

    // place (bucket-grouped in LDS)
    for (int k = 0; k < EPW / 256; ++k) {
        int e = e0 + k * 256 + tid;
        if (e < NE) {
            int s = ei[e];
            u32 d = (u32)dstp[e];
            int b = d / BNODES;
            int p = lofs[b] + atomicAdd(&cur[b], 1);
            vals[p] = (u32)s | ((d - (u32)b * BNODES) << 16);
            bkt[p] = (u16)b;
        }
    }
    __syncthreads();

    // claim global chunks
    for (int b = tid; b < NB; b += 256) {
        int c = cur[b];
        gb[b] = c ? atomicAdd(&gcnt[b], c) : 0;
    }
    __syncthreads();

    // flush bucket-grouped -> contiguous runs per bucket
    for (int idx = tid; idx < nE; idx += 256) {
        int b = bkt[idx];
        ebuf[(size_t)b * BCAP + gb[b] + (idx - lofs[b])] = vals[idx];
    }
}

// ---------------- gather: z[i] = h[i] + sum_{j->i} h[j], per-bucket LDS accum
// block = bucket (<=49 nodes); f32 accumulators in LDS; edge-parallel waves.

__global__ __launch_bounds__(256) void gather_acc_kernel(
    const u16* __restrict__ h, const u32* __restrict__ ebuf,
    const int* __restrict__ gcnt, u16* __restrict__ z)
{
    __shared__ float acc[BNODES * FD];   // 25,088 B -> 6 WG/CU
    const int tid = threadIdx.x, lane = tid & 63, wv = tid >> 6;
    const int b = blockIdx.x;
    const int node0 = b * BNODES;
    const int nNodes = min(BNODES, NN - node0);

    // self term
    for (int idx = tid; idx < nNodes * 64; idx += 256) {
        int n = idx >> 6, fp = idx & 63;
        u32 v = *reinterpret_cast<const u32*>(h + (size_t)(node0 + n) * FD + fp * 2);
        acc[n * FD + fp * 2]     = b2f((u16)(v & 0xFFFF));
        acc[n * FD + fp * 2 + 1] = b2f((u16)(v >> 16));
    }
    __syncthreads();

    const int cnt = gcnt[b];
    const u32* eb = ebuf + (size_t)b * BCAP;

    for (int base = wv * 8; base < cnt; base += 32) {
        u32 pk[8], rw[8];
#pragma unroll
        for (int u = 0; u < 8; ++u) {
            int e = base + u;
            pk[u] = (e < cnt) ? eb[e] : 0xFFFFFFFFu;   // sentinel: never a real value
        }
#pragma unroll
        for (int u = 0; u < 8; ++u) {
            if (pk[u] != 0xFFFFFFFFu) {
                int s = pk[u] & 0xFFFF;
                rw[u] = *reinterpret_cast<const u32*>(h + (size_t)s * FD + lane * 2);
            }
        }
#pragma unroll
        for (int u = 0; u < 8; ++u) {
            if (pk[u] != 0xFFFFFFFFu) {
                int nl = (pk[u] >> 16) & 0x7F;
                atomicAdd(&acc[nl * FD + lane * 2],     b2f((u16)(rw[u] & 0xFFFF)));
                atomicAdd(&acc[nl * FD + lane * 2 + 1], b2f((u16)(rw[u] >> 16)));
            }
        }
    }
    __syncthreads();

    for (int idx = tid; idx < nNodes * 64; idx += 256) {
        int n = idx >> 6, fp = idx & 63;
        u32 o = (u32)f2b(acc[n * FD + fp * 2]) |
                ((u32)f2b(acc[n * FD + fp * 2 + 1]) << 16);
        *reinterpret_cast<u32*>(z + (size_t)(node0 + n) * FD + fp * 2) = o;
    }
}

// ---------------- MFMA GEMM: out = relu(A @ W + bias) ----------------
// A [NN][128] bf16; WT [128][128] bf16 = W^T. 64 rows x 128 cols per block,
// 4 waves as 2Mx2N. k-map phi(g,i)=8g+i both operands; D: col=lane&15,
// row=(lane>>4)*4+reg  [m89-verified].

template <bool F32OUT>
__global__ __launch_bounds__(256) void gemm_mfma_kernel(
    const u16* __restrict__ A, const u16* __restrict__ WT,
    const float* __restrict__ bias, void* __restrict__ outv)
{
    __shared__ u16 a_lds[64][136];
    __shared__ u16 w_lds[128][136];

    const int tid = threadIdx.x;
    const int lane = tid & 63;
    const int wv = tid >> 6;
    const int row0 = blockIdx.x * 64;
    const int g = lane >> 4;
    const int l16 = lane & 15;

#pragma unroll
    for (int it = 0; it < 8; ++it) {
        int idx = tid + it * 256;
        int r = idx >> 4, c = (idx & 15) * 8;
        *reinterpret_cast<bf16x8*>(&w_lds[r][c]) =
            *reinterpret_cast<const bf16x8*>(WT + (size_t)r * FD + c);
    }
#pragma unroll
    for (int it = 0; it < 4; ++it) {
        int idx = tid + it * 256;
        int r = idx >> 4, c = (idx & 15) * 8;
        int grow = row0 + r; if (grow >= NN) grow = NN - 1;
        *reinterpret_cast<bf16x8*>(&a_lds[r][c]) =
            *reinterpret_cast<const bf16x8*>(A + (size_t)grow * FD + c);
    }
    __syncthreads();

    const int mbase = (wv >> 1) * 32;
    const int nbase = (wv & 1) * 64;

    f32x4 acc[2][4];
#pragma unroll
    for (int m = 0; m < 2; ++m)
#pragma unroll
        for (int nf = 0; nf < 4; ++nf) acc[m][nf] = (f32x4){0.f, 0.f, 0.f, 0.f};

#pragma unroll
    for (int k0 = 0; k0 < 4; ++k0) {
        const int kk = k0 * 32 + g * 8;
        bf16x8 a0 = *reinterpret_cast<const bf16x8*>(&a_lds[mbase + l16][kk]);
        bf16x8 a1 = *reinterpret_cast<const bf16x8*>(&a_lds[mbase + 16 + l16][kk]);
#pragma unroll
        for (int nf = 0; nf < 4; ++nf) {
            bf16x8 b = *reinterpret_cast<const bf16x8*>(&w_lds[nbase + nf * 16 + l16][kk]);
            acc[0][nf] = __builtin_amdgcn_mfma_f32_16x16x32_bf16(a0, b, acc[0][nf], 0, 0, 0);
            acc[1][nf] = __builtin_amdgcn_mfma_f32_16x16x32_bf16(a1, b, acc[1][nf], 0, 0, 0);
        }
    }

#pragma unroll
    for (int m = 0; m < 2; ++m) {
#pragma unroll
        for (int nf = 0; nf < 4; ++nf) {
            int col = nbase + nf * 16 + l16;
            float bc = bias[col];
#pragma unroll
            for (int r = 0; r < 4; ++r) {
                int row = row0 + mbase + 16 * m + g * 4 + r;
                if (row < NN) {
                    float v = fmaxf(acc[m][nf][r] + bc, 0.f);
                    if (F32OUT)
                        reinterpret_cast<float*>(outv)[(size_t)row * FD + col] = v;
                    else
                        reinterpret_cast<u16*>(outv)[(size_t)row * FD + col] = f2b(v);
                }
            }
        }
    }
}

extern "C" void kernel_launch(void* const* d_in, const int* in_sizes, int n_in,
                              void* d_out, int out_size, void* d_ws, size_t ws_size,
                              hipStream_t stream) {
    const float* x   = (const float*)d_in[0];
    const int*   ei  = (const int*)d_in[1];
    const float* W1a = (const float*)d_in[2];
    const float* b1a = (const float*)d_in[3];
    const float* W1b = (const float*)d_in[4];
    const float* b1b = (const float*)d_in[5];
    const float* W2a = (const float*)d_in[6];
    const float* b2a = (const float*)d_in[7];
    const float* W2b = (const float*)d_in[8];
    const float* b2b = (const float*)d_in[9];

    const size_t feat = (size_t)NN * FD;
    u16* xb = (u16*)d_ws;             // 12.8 MB (x, later h1)
    u16* zb = xb + feat;              // 12.8 MB
    u16* tb = zb + feat;              // 12.8 MB
    u16* wt = tb + feat;              // 128 KB
    int* gcnt = (int*)(wt + 4 * FD * FD);       // 1024 ints
    u32* ebuf = (u32*)(gcnt + 1024);            // NB*BCAP*4 = 5.23 MB

    const int cBlocks = (int)(feat / (256 * 8));// 3125
    const int mBlocks = (NN + 63) / 64;         // 782

    convert_x_kernel<<<cBlocks, 256, 0, stream>>>(x, xb);
    convert_w_kernel<<<4, 256, 0, stream>>>(W1a, W1b, W2a, W2b, wt);

    hipMemsetAsync(gcnt, 0, NB * sizeof(int), stream);
    bin_kernel<<<NWG_BIN, 256, 0, stream>>>(ei, ebuf, gcnt);

    // conv1
    gather_acc_kernel<<<NB, 256, 0, stream>>>(xb, ebuf, gcnt, zb);
    gemm_mfma_kernel<false><<<mBlocks, 256, 0, stream>>>(zb, wt,              b1a, tb);
    gemm_mfma_kernel<false><<<mBlocks, 256, 0, stream>>>(tb, wt + 1 * FD*FD,  b1b, xb);

    // conv2
    gather_acc_kernel<<<NB, 256, 0, stream>>>(xb, ebuf, gcnt, zb);
    gemm_mfma_kernel<false><<<mBlocks, 256, 0, stream>>>(zb, wt + 2 * FD*FD,  b2a, tb);
    gemm_mfma_kernel<true ><<<mBlocks, 256, 0, stream>>>(tb, wt + 3 * FD*FD,  b2b, (float*)d_out);
}

// Round 5
// 172.108 us; speedup vs baseline: 6.7681x; 6.7681x over previous
//
#include <hip/hip_runtime.h>

// GIN: 2x GINConv(eps=0), N=50000, E=800000, d=128. bf16 + MFMA.
// R5: bin-by-(dst>>6) with LDS-staged contiguous flush (no false sharing),
// then per-bucket LDS counting-sort -> per-node REGISTER-accumulate gather
// (R4's LDS-atomic accumulate was a 102M-serialized-ds_add disaster; reverted
// to R3's register+shfl structure).
// ws: [ xb 12.8M | zb 12.8M | tb 12.8M | wt 128K | gcnt 4K | ebuf 4.8M ]

#define NN 50000
#define NE 800000
#define FD 128
#define BNODES 64
#define NB 782           // ceil(NN/64); bucket 781 has 16 nodes
#define BCAP 1536        // max edges/bucket: mean 1024, sigma 32 -> +16 sigma
#define EPW 4096
#define NWG_BIN 196      // ceil(NE/EPW)

typedef unsigned short u16;
typedef unsigned int u32;
typedef __attribute__((ext_vector_type(8))) short bf16x8;
typedef __attribute__((ext_vector_type(4))) float f32x4;

static __device__ __forceinline__ float b2f(u16 u) {
    return __uint_as_float(((u32)u) << 16);
}
static __device__ __forceinline__ u16 f2b(float f) {
    u32 x = __float_as_uint(f);
    u32 r = x + 0x7FFFu + ((x >> 16) & 1u);   // RNE
    return (u16)(r >> 16);
}

// ---------------- converts ----------------

__global__ __launch_bounds__(256) void convert_x_kernel(
    const float* __restrict__ x, u16* __restrict__ xb)
{
    int gid = blockIdx.x * 256 + threadIdx.x;
    size_t base = (size_t)gid * 8;
    float4 a = *reinterpret_cast<const float4*>(x + base);
    float4 b = *reinterpret_cast<const float4*>(x + base + 4);
    u32 w0 = (u32)f2b(a.x) | ((u32)f2b(a.y) << 16);
    u32 w1 = (u32)f2b(a.z) | ((u32)f2b(a.w) << 16);
    u32 w2 = (u32)f2b(b.x) | ((u32)f2b(b.y) << 16);
    u32 w3 = (u32)f2b(b.z) | ((u32)f2b(b.w) << 16);
    uint4 o = {w0, w1, w2, w3};
    *reinterpret_cast<uint4*>(xb + base) = o;
}

// W [128][128] fp32 row-major -> WT[n][k] = W[k][n] bf16
__global__ __launch_bounds__(256) void convert_w_kernel(
    const float* __restrict__ w0, const float* __restrict__ w1,
    const float* __restrict__ w2, const float* __restrict__ w3,
    u16* __restrict__ wt)
{
    int b = blockIdx.x;
    const float* W = (b == 0) ? w0 : (b == 1) ? w1 : (b == 2) ? w2 : w3;
    u16* out = wt + (size_t)b * FD * FD;
    for (int idx = threadIdx.x; idx < FD * FD; idx += 256) {
        int n = idx >> 7, k = idx & 127;
        out[idx] = f2b(W[k * FD + n]);
    }
}

// ---------------- bucket binning ----------------
// Edges grouped by bucket b = dst>>6 into ebuf[b*BCAP ...], packed
// u32 = src | (dst_local << 16). Order within bucket irrelevant.

__global__ __launch_bounds__(256) void bin_kernel(
    const int* __restrict__ ei, u32* __restrict__ ebuf, int* __restrict__ gcnt)
{
    __shared__ int cnt[1024];
    __shared__ int lofs[1024];
    __shared__ int cur[1024];
    __shared__ int gb[1024];
    __shared__ int csum[16];
    __shared__ int cofs[16];
    __shared__ u32 vals[EPW];
    __shared__ u16 bkt[EPW];

    const int tid = threadIdx.x, lane = tid & 63, wv = tid >> 6;
    const int e0 = blockIdx.x * EPW;
    const int nE = min(EPW, NE - e0);
    const int* dstp = ei + NE;

    for (int i = tid; i < 1024; i += 256) { cnt[i] = 0; cur[i] = 0; }
    __syncthreads();

    for (int k = 0; k < EPW / 256; ++k) {
        int e = e0 + k * 256 + tid;
        if (e < NE) atomicAdd(&cnt[(u32)dstp[e] >> 6], 1);
    }
    __syncthreads();

    // exclusive scan over 1024 slots (16 chunks of 64)
    for (int cc = 0; cc < 4; ++cc) {
        int c = wv + cc * 4;
        int i = c * 64 + lane;
        int v = cnt[i];
        int sc = v;
#pragma unroll
        for (int s = 1; s < 64; s <<= 1) {
            int t = __shfl_up(sc, s);
            if (lane >= s) sc += t;
        }
        lofs[i] = sc - v;
        if (lane == 63) csum[c] = sc;
    }
    __syncthreads();
    if (wv == 0) {
        int s = (lane < 16) ? csum[lane] : 0;
        int sc = s;
#pragma unroll
        for (int st = 1; st < 16; st <<= 1) {
            int t = __shfl_up(sc, st);
            if (lane >= st) sc += t;
        }
        if (lane < 16) cofs[lane] = sc - s;
    }
    __syncthreads();
    for (int cc = 0; cc < 4; ++cc) {
        int c = wv + cc * 4;
        lofs[c * 64 + lane] += cofs[c];
    }
    __syncthreads();

    // place (bucket-grouped in LDS)
    for (int k = 0; k < EPW / 256; ++k) {
        int e = e0 + k * 256 + tid;
        if (e < NE) {
            int s = ei[e];
            u32 d = (u32)dstp[e];
            int b = d >> 6;
            int p = lofs[b] + atomicAdd(&cur[b], 1);
            vals[p] = (u32)s | ((d & 63u) << 16);
            bkt[p] = (u16)b;
        }
    }
    __syncthreads();

    // claim global chunks
    for (int b = tid; b < NB; b += 256) {
        int c = cur[b];
        gb[b] = c ? atomicAdd(&gcnt[b], c) : 0;
    }
    __syncthreads();

    // flush bucket-grouped -> contiguous runs
    for (int idx = tid; idx < nE; idx += 256) {
        int b = bkt[idx];
        ebuf[(size_t)b * BCAP + gb[b] + (idx - lofs[b])] = vals[idx];
    }
}

// ---------------- gather: counting-sort bucket edges, then per-node
// register-accumulate (wave per node, 2 edges in flight via 32-lane halves).

__global__ __launch_bounds__(256) void gather_sort_kernel(
    const u16* __restrict__ h, const u32* __restrict__ ebuf,
    const int* __restrict__ gcnt, u16* __restrict__ z)
{
    __shared__ u32 stage[BCAP];    // 6 KB
    __shared__ u16 sorted[BCAP];   // 3 KB
    __shared__ int cnt64[64];
    __shared__ int off64[65];
    __shared__ int cur64[64];

    const int tid = threadIdx.x, lane = tid & 63, wv = tid >> 6;
    const int b = blockIdx.x;
    const int node0 = b * BNODES;
    const int nNodes = min(BNODES, NN - node0);
    const int cnt = gcnt[b];
    const u32* eb = ebuf + (size_t)b * BCAP;

    if (tid < 64) cnt64[tid] = 0;
    __syncthreads();

    for (int e = tid; e < cnt; e += 256) {
        u32 v = eb[e];
        stage[e] = v;
        atomicAdd(&cnt64[v >> 16], 1);
    }
    __syncthreads();

    if (wv == 0) {
        int v = cnt64[lane];
        int sc = v;
#pragma unroll
        for (int s = 1; s < 64; s <<= 1) {
            int t = __shfl_up(sc, s);
            if (lane >= s) sc += t;
        }
        off64[lane + 1] = sc;
        cur64[lane] = sc - v;
        if (lane == 0) off64[0] = 0;
    }
    __syncthreads();

    for (int e = tid; e < cnt; e += 256) {
        u32 v = stage[e];
        int pos = atomicAdd(&cur64[v >> 16], 1);
        sorted[pos] = (u16)(v & 0xFFFFu);
    }
    __syncthreads();

    const int half = lane >> 5;
    const int c4 = (lane & 31) * 4;

    for (int n = wv; n < nNodes; n += 4) {
        const int node = node0 + n;
        const int beg = off64[n];
        const int end = off64[n + 1];

        float4 acc = {0.f, 0.f, 0.f, 0.f};
        if (half == 0) {
            ushort4 s = *reinterpret_cast<const ushort4*>(h + (size_t)node * FD + c4);
            acc.x = b2f(s.x); acc.y = b2f(s.y); acc.z = b2f(s.z); acc.w = b2f(s.w);
        }

        int e = beg + half;    // this half's edges: beg+half, +2, +4, ...
        for (; e + 6 < end; e += 8) {
            int s0 = sorted[e], s1 = sorted[e + 2], s2 = sorted[e + 4], s3 = sorted[e + 6];
            ushort4 v0 = *reinterpret_cast<const ushort4*>(h + (size_t)s0 * FD + c4);
            ushort4 v1 = *reinterpret_cast<const ushort4*>(h + (size_t)s1 * FD + c4);
            ushort4 v2 = *reinterpret_cast<const ushort4*>(h + (size_t)s2 * FD + c4);
            ushort4 v3 = *reinterpret_cast<const ushort4*>(h + (size_t)s3 * FD + c4);
            acc.x += b2f(v0.x); acc.y += b2f(v0.y); acc.z += b2f(v0.z); acc.w += b2f(v0.w);
            acc.x += b2f(v1.x); acc.y += b2f(v1.y); acc.z += b2f(v1.z); acc.w += b2f(v1.w);
            acc.x += b2f(v2.x); acc.y += b2f(v2.y); acc.z += b2f(v2.z); acc.w += b2f(v2.w);
            acc.x += b2f(v3.x); acc.y += b2f(v3.y); acc.z += b2f(v3.z); acc.w += b2f(v3.w);
        }
        for (; e < end; e += 2) {
            int s = sorted[e];
            ushort4 v = *reinterpret_cast<const ushort4*>(h + (size_t)s * FD + c4);
            acc.x += b2f(v.x); acc.y += b2f(v.y); acc.z += b2f(v.z); acc.w += b2f(v.w);
        }

        acc.x += __shfl_xor(acc.x, 32);
        acc.y += __shfl_xor(acc.y, 32);
        acc.z += __shfl_xor(acc.z, 32);
        acc.w += __shfl_xor(acc.w, 32);
        if (half == 0) {
            ushort4 o = {f2b(acc.x), f2b(acc.y), f2b(acc.z), f2b(acc.w)};
            *reinterpret_cast<ushort4*>(z + (size_t)node * FD + c4) = o;
        }
    }
}

// ---------------- MFMA GEMM: out = relu(A @ W + bias) ----------------
// A [NN][128] bf16; WT [128][128] bf16 = W^T. 64 rows x 128 cols per block,
// 4 waves as 2Mx2N. k-map phi(g,i)=8g+i both operands; D: col=lane&15,
// row=(lane>>4)*4+reg  [m89-verified].

template <bool F32OUT>
__global__ __launch_bounds__(256) void gemm_mfma_kernel(
    const u16* __restrict__ A, const u16* __restrict__ WT,
    const float* __restrict__ bias, void* __restrict__ outv)
{
    __shared__ u16 a_lds[64][136];
    __shared__ u16 w_lds[128][136];

    const int tid = threadIdx.x;
    const int lane = tid & 63;
    const int wv = tid >> 6;
    const int row0 = blockIdx.x * 64;
    const int g = lane >> 4;
    const int l16 = lane & 15;

#pragma unroll
    for (int it = 0; it < 8; ++it) {
        int idx = tid + it * 256;
        int r = idx >> 4, c = (idx & 15) * 8;
        *reinterpret_cast<bf16x8*>(&w_lds[r][c]) =
            *reinterpret_cast<const bf16x8*>(WT + (size_t)r * FD + c);
    }
#pragma unroll
    for (int it = 0; it < 4; ++it) {
        int idx = tid + it * 256;
        int r = idx >> 4, c = (idx & 15) * 8;
        int grow = row0 + r; if (grow >= NN) grow = NN - 1;
        *reinterpret_cast<bf16x8*>(&a_lds[r][c]) =
            *reinterpret_cast<const bf16x8*>(A + (size_t)grow * FD + c);
    }
    __syncthreads();

    const int mbase = (wv >> 1) * 32;
    const int nbase = (wv & 1) * 64;

    f32x4 acc[2][4];
#pragma unroll
    for (int m = 0; m < 2; ++m)
#pragma unroll
        for (int nf = 0; nf < 4; ++nf) acc[m][nf] = (f32x4){0.f, 0.f, 0.f, 0.f};

#pragma unroll
    for (int k0 = 0; k0 < 4; ++k0) {
        const int kk = k0 * 32 + g * 8;
        bf16x8 a0 = *reinterpret_cast<const bf16x8*>(&a_lds[mbase + l16][kk]);
        bf16x8 a1 = *reinterpret_cast<const bf16x8*>(&a_lds[mbase + 16 + l16][kk]);
#pragma unroll
        for (int nf = 0; nf < 4; ++nf) {
            bf16x8 b = *reinterpret_cast<const bf16x8*>(&w_lds[nbase + nf * 16 + l16][kk]);
            acc[0][nf] = __builtin_amdgcn_mfma_f32_16x16x32_bf16(a0, b, acc[0][nf], 0, 0, 0);
            acc[1][nf] = __builtin_amdgcn_mfma_f32_16x16x32_bf16(a1, b, acc[1][nf], 0, 0, 0);
        }
    }

#pragma unroll
    for (int m = 0; m < 2; ++m) {
#pragma unroll
        for (int nf = 0; nf < 4; ++nf) {
            int col = nbase + nf * 16 + l16;
            float bc = bias[col];
#pragma unroll
            for (int r = 0; r < 4; ++r) {
                int row = row0 + mbase + 16 * m + g * 4 + r;
                if (row < NN) {
                    float v = fmaxf(acc[m][nf][r] + bc, 0.f);
                    if (F32OUT)
                        reinterpret_cast<float*>(outv)[(size_t)row * FD + col] = v;
                    else
                        reinterpret_cast<u16*>(outv)[(size_t)row * FD + col] = f2b(v);
                }
            }
        }
    }
}

extern "C" void kernel_launch(void* const* d_in, const int* in_sizes, int n_in,
                              void* d_out, int out_size, void* d_ws, size_t ws_size,
                              hipStream_t stream) {
    const float* x   = (const float*)d_in[0];
    const int*   ei  = (const int*)d_in[1];
    const float* W1a = (const float*)d_in[2];
    const float* b1a = (const float*)d_in[3];
    const float* W1b = (const float*)d_in[4];
    const float* b1b = (const float*)d_in[5];
    const float* W2a = (const float*)d_in[6];
    const float* b2a = (const float*)d_in[7];
    const float* W2b = (const float*)d_in[8];
    const float* b2b = (const float*)d_in[9];

    const size_t feat = (size_t)NN * FD;
    u16* xb = (u16*)d_ws;             // 12.8 MB (x, later h1)
    u16* zb = xb + feat;              // 12.8 MB
    u16* tb = zb + feat;              // 12.8 MB
    u16* wt = tb + feat;              // 128 KB
    int* gcnt = (int*)(wt + 4 * FD * FD);       // 1024 ints
    u32* ebuf = (u32*)(gcnt + 1024);            // NB*BCAP*4 = 4.80 MB

    const int cBlocks = (int)(feat / (256 * 8));// 3125
    const int mBlocks = (NN + 63) / 64;         // 782

    convert_x_kernel<<<cBlocks, 256, 0, stream>>>(x, xb);
    convert_w_kernel<<<4, 256, 0, stream>>>(W1a, W1b, W2a, W2b, wt);

    hipMemsetAsync(gcnt, 0, NB * sizeof(int), stream);
    bin_kernel<<<NWG_BIN, 256, 0, stream>>>(ei, ebuf, gcnt);

    // conv1
    gather_sort_kernel<<<NB, 256, 0, stream>>>(xb, ebuf, gcnt, zb);
    gemm_mfma_kernel<false><<<mBlocks, 256, 0, stream>>>(zb, wt,              b1a, tb);
    gemm_mfma_kernel<false><<<mBlocks, 256, 0, stream>>>(tb, wt + 1 * FD*FD,  b1b, xb);

    // conv2
    gather_sort_kernel<<<NB, 256, 0, stream>>>(xb, ebuf, gcnt, zb);
    gemm_mfma_kernel<false><<<mBlocks, 256, 0, stream>>>(zb, wt + 2 * FD*FD,  b2a, tb);
    gemm_mfma_kernel<true ><<<mBlocks, 256, 0, stream>>>(tb, wt + 3 * FD*FD,  b2b, (float*)d_out);
}

// Round 6
// 149.727 us; speedup vs baseline: 7.7799x; 1.1495x over previous
//
#include <hip/hip_runtime.h>

// GIN: 2x GINConv(eps=0), N=50000, E=800000, d=128. bf16 + MFMA.
// R6: (1) gather blocks widened to 512 threads (12 -> 24 waves/CU; gather was
// grid-limited latency-bound). (2) Each conv's two GEMMs fused into one
// kernel: GEMM1 -> relu -> t in LDS (D->A relayout) -> GEMM2 -> store.
// Weights NOT LDS-staged (L2-resident, read as B-frags from global) to fit
// a_lds + t_lds in 35 KB.
// ws: [ xb 12.8M | zb 12.8M | wt 128K | gcnt 4K | ebuf 4.8M ]

#define NN 50000
#define NE 800000
#define FD 128
#define BNODES 64
#define NB 782           // ceil(NN/64); bucket 781 has 16 nodes
#define BCAP 1536        // max edges/bucket: mean 1024, sigma 32 -> +16 sigma
#define EPW 4096
#define NWG_BIN 196      // ceil(NE/EPW)

typedef unsigned short u16;
typedef unsigned int u32;
typedef __attribute__((ext_vector_type(8))) short bf16x8;
typedef __attribute__((ext_vector_type(4))) float f32x4;

static __device__ __forceinline__ float b2f(u16 u) {
    return __uint_as_float(((u32)u) << 16);
}
static __device__ __forceinline__ u16 f2b(float f) {
    u32 x = __float_as_uint(f);
    u32 r = x + 0x7FFFu + ((x >> 16) & 1u);   // RNE
    return (u16)(r >> 16);
}

// ---------------- converts ----------------

__global__ __launch_bounds__(256) void convert_x_kernel(
    const float* __restrict__ x, u16* __restrict__ xb)
{
    int gid = blockIdx.x * 256 + threadIdx.x;
    size_t base = (size_t)gid * 8;
    float4 a = *reinterpret_cast<const float4*>(x + base);
    float4 b = *reinterpret_cast<const float4*>(x + base + 4);
    u32 w0 = (u32)f2b(a.x) | ((u32)f2b(a.y) << 16);
    u32 w1 = (u32)f2b(a.z) | ((u32)f2b(a.w) << 16);
    u32 w2 = (u32)f2b(b.x) | ((u32)f2b(b.y) << 16);
    u32 w3 = (u32)f2b(b.z) | ((u32)f2b(b.w) << 16);
    uint4 o = {w0, w1, w2, w3};
    *reinterpret_cast<uint4*>(xb + base) = o;
}

// W [128][128] fp32 row-major -> WT[n][k] = W[k][n] bf16
__global__ __launch_bounds__(256) void convert_w_kernel(
    const float* __restrict__ w0, const float* __restrict__ w1,
    const float* __restrict__ w2, const float* __restrict__ w3,
    u16* __restrict__ wt)
{
    int b = blockIdx.x;
    const float* W = (b == 0) ? w0 : (b == 1) ? w1 : (b == 2) ? w2 : w3;
    u16* out = wt + (size_t)b * FD * FD;
    for (int idx = threadIdx.x; idx < FD * FD; idx += 256) {
        int n = idx >> 7, k = idx & 127;
        out[idx] = f2b(W[k * FD + n]);
    }
}

// ---------------- bucket binning ----------------
// Edges grouped by bucket b = dst>>6 into ebuf[b*BCAP ...], packed
// u32 = src | (dst_local << 16). Order within bucket irrelevant.

__global__ __launch_bounds__(256) void bin_kernel(
    const int* __restrict__ ei, u32* __restrict__ ebuf, int* __restrict__ gcnt)
{
    __shared__ int cnt[1024];
    __shared__ int lofs[1024];
    __shared__ int cur[1024];
    __shared__ int gb[1024];
    __shared__ int csum[16];
    __shared__ int cofs[16];
    __shared__ u32 vals[EPW];
    __shared__ u16 bkt[EPW];

    const int tid = threadIdx.x, lane = tid & 63, wv = tid >> 6;
    const int e0 = blockIdx.x * EPW;
    const int nE = min(EPW, NE - e0);
    const int* dstp = ei + NE;

    for (int i = tid; i < 1024; i += 256) { cnt[i] = 0; cur[i] = 0; }
    __syncthreads();

    for (int k = 0; k < EPW / 256; ++k) {
        int e = e0 + k * 256 + tid;
        if (e < NE) atomicAdd(&cnt[(u32)dstp[e] >> 6], 1);
    }
    __syncthreads();

    // exclusive scan over 1024 slots (16 chunks of 64)
    for (int cc = 0; cc < 4; ++cc) {
        int c = wv + cc * 4;
        int i = c * 64 + lane;
        int v = cnt[i];
        int sc = v;
#pragma unroll
        for (int s = 1; s < 64; s <<= 1) {
            int t = __shfl_up(sc, s);
            if (lane >= s) sc += t;
        }
        lofs[i] = sc - v;
        if (lane == 63) csum[c] = sc;
    }
    __syncthreads();
    if (wv == 0) {
        int s = (lane < 16) ? csum[lane] : 0;
        int sc = s;
#pragma unroll
        for (int st = 1; st < 16; st <<= 1) {
            int t = __shfl_up(sc, st);
            if (lane >= st) sc += t;
        }
        if (lane < 16) cofs[lane] = sc - s;
    }
    __syncthreads();
    for (int cc = 0; cc < 4; ++cc) {
        int c = wv + cc * 4;
        lofs[c * 64 + lane] += cofs[c];
    }
    __syncthreads();

    // place (bucket-grouped in LDS)
    for (int k = 0; k < EPW / 256; ++k) {
        int e = e0 + k * 256 + tid;
        if (e < NE) {
            int s = ei[e];
            u32 d = (u32)dstp[e];
            int b = d >> 6;
            int p = lofs[b] + atomicAdd(&cur[b], 1);
            vals[p] = (u32)s | ((d & 63u) << 16);
            bkt[p] = (u16)b;
        }
    }
    __syncthreads();

    // claim global chunks
    for (int b = tid; b < NB; b += 256) {
        int c = cur[b];
        gb[b] = c ? atomicAdd(&gcnt[b], c) : 0;
    }
    __syncthreads();

    // flush bucket-grouped -> contiguous runs
    for (int idx = tid; idx < nE; idx += 256) {
        int b = bkt[idx];
        ebuf[(size_t)b * BCAP + gb[b] + (idx - lofs[b])] = vals[idx];
    }
}

// ---------------- gather: counting-sort bucket edges, then per-node
// register-accumulate. 512 threads (8 waves) for TLP: gather was
// grid-limited at 12 waves/CU with 256-thread blocks.

__global__ __launch_bounds__(512) void gather_sort_kernel(
    const u16* __restrict__ h, const u32* __restrict__ ebuf,
    const int* __restrict__ gcnt, u16* __restrict__ z)
{
    __shared__ u32 stage[BCAP];    // 6 KB
    __shared__ u16 sorted[BCAP];   // 3 KB
    __shared__ int cnt64[64];
    __shared__ int off64[65];
    __shared__ int cur64[64];

    const int tid = threadIdx.x, lane = tid & 63, wv = tid >> 6;
    const int b = blockIdx.x;
    const int node0 = b * BNODES;
    const int nNodes = min(BNODES, NN - node0);
    const int cnt = gcnt[b];
    const u32* eb = ebuf + (size_t)b * BCAP;

    if (tid < 64) cnt64[tid] = 0;
    __syncthreads();

    for (int e = tid; e < cnt; e += 512) {
        u32 v = eb[e];
        stage[e] = v;
        atomicAdd(&cnt64[v >> 16], 1);
    }
    __syncthreads();

    if (wv == 0) {
        int v = cnt64[lane];
        int sc = v;
#pragma unroll
        for (int s = 1; s < 64; s <<= 1) {
            int t = __shfl_up(sc, s);
            if (lane >= s) sc += t;
        }
        off64[lane + 1] = sc;
        cur64[lane] = sc - v;
        if (lane == 0) off64[0] = 0;
    }
    __syncthreads();

    for (int e = tid; e < cnt; e += 512) {
        u32 v = stage[e];
        int pos = atomicAdd(&cur64[v >> 16], 1);
        sorted[pos] = (u16)(v & 0xFFFFu);
    }
    __syncthreads();

    const int half = lane >> 5;
    const int c4 = (lane & 31) * 4;

    for (int n = wv; n < nNodes; n += 8) {
        const int node = node0 + n;
        const int beg = off64[n];
        const int end = off64[n + 1];

        float4 acc = {0.f, 0.f, 0.f, 0.f};
        if (half == 0) {
            ushort4 s = *reinterpret_cast<const ushort4*>(h + (size_t)node * FD + c4);
            acc.x = b2f(s.x); acc.y = b2f(s.y); acc.z = b2f(s.z); acc.w = b2f(s.w);
        }

        int e = beg + half;    // this half's edges: beg+half, +2, +4, ...
        for (; e + 6 < end; e += 8) {
            int s0 = sorted[e], s1 = sorted[e + 2], s2 = sorted[e + 4], s3 = sorted[e + 6];
            ushort4 v0 = *reinterpret_cast<const ushort4*>(h + (size_t)s0 * FD + c4);
            ushort4 v1 = *reinterpret_cast<const ushort4*>(h + (size_t)s1 * FD + c4);
            ushort4 v2 = *reinterpret_cast<const ushort4*>(h + (size_t)s2 * FD + c4);
            ushort4 v3 = *reinterpret_cast<const ushort4*>(h + (size_t)s3 * FD + c4);
            acc.x += b2f(v0.x); acc.y += b2f(v0.y); acc.z += b2f(v0.z); acc.w += b2f(v0.w);
            acc.x += b2f(v1.x); acc.y += b2f(v1.y); acc.z += b2f(v1.z); acc.w += b2f(v1.w);
            acc.x += b2f(v2.x); acc.y += b2f(v2.y); acc.z += b2f(v2.z); acc.w += b2f(v2.w);
            acc.x += b2f(v3.x); acc.y += b2f(v3.y); acc.z += b2f(v3.z); acc.w += b2f(v3.w);
        }
        for (; e < end; e += 2) {
            int s = sorted[e];
            ushort4 v = *reinterpret_cast<const ushort4*>(h + (size_t)s * FD + c4);
            acc.x += b2f(v.x); acc.y += b2f(v.y); acc.z += b2f(v.z); acc.w += b2f(v.w);
        }

        acc.x += __shfl_xor(acc.x, 32);
        acc.y += __shfl_xor(acc.y, 32);
        acc.z += __shfl_xor(acc.z, 32);
        acc.w += __shfl_xor(acc.w, 32);
        if (half == 0) {
            ushort4 o = {f2b(acc.x), f2b(acc.y), f2b(acc.z), f2b(acc.w)};
            *reinterpret_cast<ushort4*>(z + (size_t)node * FD + c4) = o;
        }
    }
}

// ---------------- fused MLP: out = relu(relu(A@Wa+ba)@Wb+bb) ----------------
// A [NN][128] bf16; WTa/WTb [128][128] bf16 = W^T (L2-resident, read as
// B-frags directly from global — no LDS staging). M=64 tile, 8 waves as
// 2Mx4N (wave = 32 rows x 32 cols). t relayout D->A via LDS.
// k-map phi(g,i)=8g+i both operands; D: col=lane&15, row=(lane>>4)*4+reg.

template <bool F32OUT>
__global__ __launch_bounds__(512) void gemm_pair_kernel(
    const u16* __restrict__ A,
    const u16* __restrict__ WTa, const float* __restrict__ biasa,
    const u16* __restrict__ WTb, const float* __restrict__ biasb,
    void* __restrict__ outv)
{
    __shared__ u16 a_lds[64][136];   // 17.4 KB
    __shared__ u16 t_lds[64][136];   // 17.4 KB

    const int tid = threadIdx.x;
    const int lane = tid & 63;
    const int wv = tid >> 6;         // 0..7
    const int row0 = blockIdx.x * 64;
    const int g = lane >> 4;
    const int l16 = lane & 15;

    // stage A tile (64x128): 1024 chunks of 8, 512 threads -> 2 iters
#pragma unroll
    for (int it = 0; it < 2; ++it) {
        int idx = tid + it * 512;
        int r = idx >> 4, c = (idx & 15) * 8;
        int grow = row0 + r; if (grow >= NN) grow = NN - 1;
        *reinterpret_cast<bf16x8*>(&a_lds[r][c]) =
            *reinterpret_cast<const bf16x8*>(A + (size_t)grow * FD + c);
    }
    __syncthreads();

    const int mbase = (wv >> 2) * 32;   // 0 or 32
    const int nbase = (wv & 3) * 32;    // 0,32,64,96

    // ---- GEMM1: t = relu(A @ Wa + ba) ----
    f32x4 acc[2][2];
#pragma unroll
    for (int m = 0; m < 2; ++m)
#pragma unroll
        for (int nf = 0; nf < 2; ++nf) acc[m][nf] = (f32x4){0.f, 0.f, 0.f, 0.f};

#pragma unroll
    for (int k0 = 0; k0 < 4; ++k0) {
        const int kk = k0 * 32 + g * 8;
        bf16x8 a0 = *reinterpret_cast<const bf16x8*>(&a_lds[mbase + l16][kk]);
        bf16x8 a1 = *reinterpret_cast<const bf16x8*>(&a_lds[mbase + 16 + l16][kk]);
#pragma unroll
        for (int nf = 0; nf < 2; ++nf) {
            bf16x8 b = *reinterpret_cast<const bf16x8*>(
                WTa + (size_t)(nbase + nf * 16 + l16) * FD + kk);
            acc[0][nf] = __builtin_amdgcn_mfma_f32_16x16x32_bf16(a0, b, acc[0][nf], 0, 0, 0);
            acc[1][nf] = __builtin_amdgcn_mfma_f32_16x16x32_bf16(a1, b, acc[1][nf], 0, 0, 0);
        }
    }

    // t -> LDS (bias + relu + bf16)
#pragma unroll
    for (int m = 0; m < 2; ++m) {
#pragma unroll
        for (int nf = 0; nf < 2; ++nf) {
            int col = nbase + nf * 16 + l16;
            float bc = biasa[col];
#pragma unroll
            for (int r = 0; r < 4; ++r) {
                int row = mbase + 16 * m + g * 4 + r;
                t_lds[row][col] = f2b(fmaxf(acc[m][nf][r] + bc, 0.f));
            }
        }
    }
    __syncthreads();

    // ---- GEMM2: out = relu(t @ Wb + bb) ----
    f32x4 acc2[2][2];
#pragma unroll
    for (int m = 0; m < 2; ++m)
#pragma unroll
        for (int nf = 0; nf < 2; ++nf) acc2[m][nf] = (f32x4){0.f, 0.f, 0.f, 0.f};

#pragma unroll
    for (int k0 = 0; k0 < 4; ++k0) {
        const int kk = k0 * 32 + g * 8;
        bf16x8 a0 = *reinterpret_cast<const bf16x8*>(&t_lds[mbase + l16][kk]);
        bf16x8 a1 = *reinterpret_cast<const bf16x8*>(&t_lds[mbase + 16 + l16][kk]);
#pragma unroll
        for (int nf = 0; nf < 2; ++nf) {
            bf16x8 b = *reinterpret_cast<const bf16x8*>(
                WTb + (size_t)(nbase + nf * 16 + l16) * FD + kk);
            acc2[0][nf] = __builtin_amdgcn_mfma_f32_16x16x32_bf16(a0, b, acc2[0][nf], 0, 0, 0);
            acc2[1][nf] = __builtin_amdgcn_mfma_f32_16x16x32_bf16(a1, b, acc2[1][nf], 0, 0, 0);
        }
    }

#pragma unroll
    for (int m = 0; m < 2; ++m) {
#pragma unroll
        for (int nf = 0; nf < 2; ++nf) {
            int col = nbase + nf * 16 + l16;
            float bc = biasb[col];
#pragma unroll
            for (int r = 0; r < 4; ++r) {
                int row = row0 + mbase + 16 * m + g * 4 + r;
                if (row < NN) {
                    float v = fmaxf(acc2[m][nf][r] + bc, 0.f);
                    if (F32OUT)
                        reinterpret_cast<float*>(outv)[(size_t)row * FD + col] = v;
                    else
                        reinterpret_cast<u16*>(outv)[(size_t)row * FD + col] = f2b(v);
                }
            }
        }
    }
}

extern "C" void kernel_launch(void* const* d_in, const int* in_sizes, int n_in,
                              void* d_out, int out_size, void* d_ws, size_t ws_size,
                              hipStream_t stream) {
    const float* x   = (const float*)d_in[0];
    const int*   ei  = (const int*)d_in[1];
    const float* W1a = (const float*)d_in[2];
    const float* b1a = (const float*)d_in[3];
    const float* W1b = (const float*)d_in[4];
    const float* b1b = (const float*)d_in[5];
    const float* W2a = (const float*)d_in[6];
    const float* b2a = (const float*)d_in[7];
    const float* W2b = (const float*)d_in[8];
    const float* b2b = (const float*)d_in[9];

    const size_t feat = (size_t)NN * FD;
    u16* xb = (u16*)d_ws;             // 12.8 MB (x, later h1)
    u16* zb = xb + feat;              // 12.8 MB
    u16* wt = zb + feat;              // 128 KB
    int* gcnt = (int*)(wt + 4 * FD * FD);       // 1024 ints
    u32* ebuf = (u32*)(gcnt + 1024);            // NB*BCAP*4 = 4.80 MB

    const int cBlocks = (int)(feat / (256 * 8));// 3125
    const int mBlocks = (NN + 63) / 64;         // 782

    convert_x_kernel<<<cBlocks, 256, 0, stream>>>(x, xb);
    convert_w_kernel<<<4, 256, 0, stream>>>(W1a, W1b, W2a, W2b, wt);

    hipMemsetAsync(gcnt, 0, NB * sizeof(int), stream);
    bin_kernel<<<NWG_BIN, 256, 0, stream>>>(ei, ebuf, gcnt);

    // conv1: gather -> fused MLP -> h1 (reuses xb)
    gather_sort_kernel<<<NB, 512, 0, stream>>>(xb, ebuf, gcnt, zb);
    gemm_pair_kernel<false><<<mBlocks, 512, 0, stream>>>(
        zb, wt, b1a, wt + 1 * FD * FD, b1b, xb);

    // conv2: gather -> fused MLP -> d_out (fp32)
    gather_sort_kernel<<<NB, 512, 0, stream>>>(xb, ebuf, gcnt, zb);
    gemm_pair_kernel<true><<<mBlocks, 512, 0, stream>>>(
        zb, wt + 2 * FD * FD, b2a, wt + 3 * FD * FD, b2b, (float*)d_out);
}

// Round 7
// 136.264 us; speedup vs baseline: 8.5485x; 1.0988x over previous
//
#include <hip/hip_runtime.h>

// GIN: 2x GINConv(eps=0), N=50000, E=800000, d=128. bf16 + MFMA.
// R7: full conv fusion. Bucket(64 nodes) == MLP M-tile(64 rows), so each conv
// is ONE kernel: load sorted edge list (LDS) -> register-accumulate gather ->
// a_lds -> GEMM1(relu) -> t_lds -> GEMM2(relu) -> store. Kills the zb round
// trip (25.6 MB/conv) + 2 launches/conv. Counting sort hoisted to a one-time
// sort_kernel (result shared by both convs).
// ws: [ xb 12.8M | zb 12.8M | wt 128K | gcnt 4K | ebuf 4.8M | sbuf 2.4M | noff 204K ]

#define NN 50000
#define NE 800000
#define FD 128
#define BNODES 64
#define NB 782           // ceil(NN/64); bucket 781 has 16 nodes
#define BCAP 1536        // max edges/bucket: mean 1024, sigma 32 -> +16 sigma
#define EPW 4096
#define NWG_BIN 196      // ceil(NE/EPW)

typedef unsigned short u16;
typedef unsigned int u32;
typedef __attribute__((ext_vector_type(8))) short bf16x8;
typedef __attribute__((ext_vector_type(4))) float f32x4;

static __device__ __forceinline__ float b2f(u16 u) {
    return __uint_as_float(((u32)u) << 16);
}
static __device__ __forceinline__ u16 f2b(float f) {
    u32 x = __float_as_uint(f);
    u32 r = x + 0x7FFFu + ((x >> 16) & 1u);   // RNE
    return (u16)(r >> 16);
}

// ---------------- converts ----------------

__global__ __launch_bounds__(256) void convert_x_kernel(
    const float* __restrict__ x, u16* __restrict__ xb)
{
    int gid = blockIdx.x * 256 + threadIdx.x;
    size_t base = (size_t)gid * 8;
    float4 a = *reinterpret_cast<const float4*>(x + base);
    float4 b = *reinterpret_cast<const float4*>(x + base + 4);
    u32 w0 = (u32)f2b(a.x) | ((u32)f2b(a.y) << 16);
    u32 w1 = (u32)f2b(a.z) | ((u32)f2b(a.w) << 16);
    u32 w2 = (u32)f2b(b.x) | ((u32)f2b(b.y) << 16);
    u32 w3 = (u32)f2b(b.z) | ((u32)f2b(b.w) << 16);
    uint4 o = {w0, w1, w2, w3};
    *reinterpret_cast<uint4*>(xb + base) = o;
}

// W [128][128] fp32 row-major -> WT[n][k] = W[k][n] bf16
__global__ __launch_bounds__(256) void convert_w_kernel(
    const float* __restrict__ w0, const float* __restrict__ w1,
    const float* __restrict__ w2, const float* __restrict__ w3,
    u16* __restrict__ wt)
{
    int b = blockIdx.x;
    const float* W = (b == 0) ? w0 : (b == 1) ? w1 : (b == 2) ? w2 : w3;
    u16* out = wt + (size_t)b * FD * FD;
    for (int idx = threadIdx.x; idx < FD * FD; idx += 256) {
        int n = idx >> 7, k = idx & 127;
        out[idx] = f2b(W[k * FD + n]);
    }
}

// ---------------- bucket binning ----------------
// Edges grouped by bucket b = dst>>6 into ebuf[b*BCAP ...], packed
// u32 = src | (dst_local << 16).

__global__ __launch_bounds__(256) void bin_kernel(
    const int* __restrict__ ei, u32* __restrict__ ebuf, int* __restrict__ gcnt)
{
    __shared__ int cnt[1024];
    __shared__ int lofs[1024];
    __shared__ int cur[1024];
    __shared__ int gb[1024];
    __shared__ int csum[16];
    __shared__ int cofs[16];
    __shared__ u32 vals[EPW];
    __shared__ u16 bkt[EPW];

    const int tid = threadIdx.x, lane = tid & 63, wv = tid >> 6;
    const int e0 = blockIdx.x * EPW;
    const int nE = min(EPW, NE - e0);
    const int* dstp = ei + NE;

    for (int i = tid; i < 1024; i += 256) { cnt[i] = 0; cur[i] = 0; }
    __syncthreads();

    for (int k = 0; k < EPW / 256; ++k) {
        int e = e0 + k * 256 + tid;
        if (e < NE) atomicAdd(&cnt[(u32)dstp[e] >> 6], 1);
    }
    __syncthreads();

    // exclusive scan over 1024 slots (16 chunks of 64)
    for (int cc = 0; cc < 4; ++cc) {
        int c = wv + cc * 4;
        int i = c * 64 + lane;
        int v = cnt[i];
        int sc = v;
#pragma unroll
        for (int s = 1; s < 64; s <<= 1) {
            int t = __shfl_up(sc, s);
            if (lane >= s) sc += t;
        }
        lofs[i] = sc - v;
        if (lane == 63) csum[c] = sc;
    }
    __syncthreads();
    if (wv == 0) {
        int s = (lane < 16) ? csum[lane] : 0;
        int sc = s;
#pragma unroll
        for (int st = 1; st < 16; st <<= 1) {
            int t = __shfl_up(sc, st);
            if (lane >= st) sc += t;
        }
        if (lane < 16) cofs[lane] = sc - s;
    }
    __syncthreads();
    for (int cc = 0; cc < 4; ++cc) {
        int c = wv + cc * 4;
        lofs[c * 64 + lane] += cofs[c];
    }
    __syncthreads();

    // place (bucket-grouped in LDS)
    for (int k = 0; k < EPW / 256; ++k) {
        int e = e0 + k * 256 + tid;
        if (e < NE) {
            int s = ei[e];
            u32 d = (u32)dstp[e];
            int b = d >> 6;
            int p = lofs[b] + atomicAdd(&cur[b], 1);
            vals[p] = (u32)s | ((d & 63u) << 16);
            bkt[p] = (u16)b;
        }
    }
    __syncthreads();

    // claim global chunks
    for (int b = tid; b < NB; b += 256) {
        int c = cur[b];
        gb[b] = c ? atomicAdd(&gcnt[b], c) : 0;
    }
    __syncthreads();

    // flush bucket-grouped -> contiguous runs
    for (int idx = tid; idx < nE; idx += 256) {
        int b = bkt[idx];
        ebuf[(size_t)b * BCAP + gb[b] + (idx - lofs[b])] = vals[idx];
    }
}

// ---------------- one-time counting sort per bucket ----------------
// ebuf (packed, unordered) -> sbuf (u16 src, grouped by dst_local) + noff.

__global__ __launch_bounds__(256) void sort_kernel(
    const u32* __restrict__ ebuf, const int* __restrict__ gcnt,
    u16* __restrict__ sbuf, int* __restrict__ noff)
{
    __shared__ u32 stage[BCAP];    // 6 KB
    __shared__ u16 sorted[BCAP];   // 3 KB
    __shared__ int cnt64[64];
    __shared__ int off64[65];
    __shared__ int cur64[64];

    const int tid = threadIdx.x, lane = tid & 63, wv = tid >> 6;
    const int b = blockIdx.x;
    const int cnt = gcnt[b];
    const u32* eb = ebuf + (size_t)b * BCAP;

    if (tid < 64) cnt64[tid] = 0;
    __syncthreads();

    for (int e = tid; e < cnt; e += 256) {
        u32 v = eb[e];
        stage[e] = v;
        atomicAdd(&cnt64[v >> 16], 1);
    }
    __syncthreads();

    if (wv == 0) {
        int v = cnt64[lane];
        int sc = v;
#pragma unroll
        for (int s = 1; s < 64; s <<= 1) {
            int t = __shfl_up(sc, s);
            if (lane >= s) sc += t;
        }
        off64[lane + 1] = sc;
        cur64[lane] = sc - v;
        if (lane == 0) off64[0] = 0;
    }
    __syncthreads();

    for (int e = tid; e < cnt; e += 256) {
        u32 v = stage[e];
        int pos = atomicAdd(&cur64[v >> 16], 1);
        sorted[pos] = (u16)(v & 0xFFFFu);   // src < 50000 fits u16
    }
    __syncthreads();

    if (tid < 65) noff[b * 65 + tid] = off64[tid];
    u32* sb = (u32*)(sbuf + (size_t)b * BCAP);
    const u32* so = (const u32*)sorted;
    for (int i = tid; i * 2 < cnt; i += 256) sb[i] = so[i];
}

// ---------------- fused conv: gather -> a_lds -> MLP (2 MFMA GEMMs) --------
// Block = bucket = M-tile (64 nodes). 8 waves.
// Gather: wave per node, 32-lane halves, register f32 accum, bf16 -> a_lds.
// GEMM: 8 waves as 2Mx4N (wave 32x64... actually 32 rows x 32 cols, 2x2 frags);
// weights read as B-frags from global (L2-resident).
// k-map phi(g,i)=8g+i both operands; D: col=lane&15, row=(lane>>4)*4+reg.

template <bool F32OUT>
__global__ __launch_bounds__(512) void conv_kernel(
    const u16* __restrict__ h, const u16* __restrict__ sbuf,
    const int* __restrict__ noff,
    const u16* __restrict__ WTa, const float* __restrict__ biasa,
    const u16* __restrict__ WTb, const float* __restrict__ biasb,
    void* __restrict__ outv)
{
    __shared__ u16 a_lds[64][136];   // 17.4 KB
    __shared__ u16 t_lds[64][136];   // 17.4 KB
    __shared__ u16 sorted[BCAP];     // 3 KB
    __shared__ int off[65];

    const int tid = threadIdx.x;
    const int lane = tid & 63;
    const int wv = tid >> 6;         // 0..7
    const int b = blockIdx.x;
    const int node0 = b * BNODES;
    const int nNodes = min(BNODES, NN - node0);
    const int g = lane >> 4;
    const int l16 = lane & 15;

    // ---- phase 1: load sorted edge list + offsets ----
    if (tid < 65) off[tid] = noff[b * 65 + tid];
    __syncthreads();
    const int cnt = off[64];
    {
        const u32* sb = (const u32*)(sbuf + (size_t)b * BCAP);
        u32* so = (u32*)sorted;
        for (int i = tid; i * 2 < cnt; i += 512) so[i] = sb[i];
    }
    __syncthreads();

    // ---- phase 2: gather into a_lds ----
    const int half = lane >> 5;
    const int c4 = (lane & 31) * 4;

    for (int n = wv; n < BNODES; n += 8) {
        if (n < nNodes) {
            const int node = node0 + n;
            const int beg = off[n];
            const int end = off[n + 1];

            float4 acc = {0.f, 0.f, 0.f, 0.f};
            if (half == 0) {
                ushort4 s = *reinterpret_cast<const ushort4*>(h + (size_t)node * FD + c4);
                acc.x = b2f(s.x); acc.y = b2f(s.y); acc.z = b2f(s.z); acc.w = b2f(s.w);
            }

            int e = beg + half;
            for (; e + 6 < end; e += 8) {
                int s0 = sorted[e], s1 = sorted[e + 2], s2 = sorted[e + 4], s3 = sorted[e + 6];
                ushort4 v0 = *reinterpret_cast<const ushort4*>(h + (size_t)s0 * FD + c4);
                ushort4 v1 = *reinterpret_cast<const ushort4*>(h + (size_t)s1 * FD + c4);
                ushort4 v2 = *reinterpret_cast<const ushort4*>(h + (size_t)s2 * FD + c4);
                ushort4 v3 = *reinterpret_cast<const ushort4*>(h + (size_t)s3 * FD + c4);
                acc.x += b2f(v0.x); acc.y += b2f(v0.y); acc.z += b2f(v0.z); acc.w += b2f(v0.w);
                acc.x += b2f(v1.x); acc.y += b2f(v1.y); acc.z += b2f(v1.z); acc.w += b2f(v1.w);
                acc.x += b2f(v2.x); acc.y += b2f(v2.y); acc.z += b2f(v2.z); acc.w += b2f(v2.w);
                acc.x += b2f(v3.x); acc.y += b2f(v3.y); acc.z += b2f(v3.z); acc.w += b2f(v3.w);
            }
            for (; e < end; e += 2) {
                int s = sorted[e];
                ushort4 v = *reinterpret_cast<const ushort4*>(h + (size_t)s * FD + c4);
                acc.x += b2f(v.x); acc.y += b2f(v.y); acc.z += b2f(v.z); acc.w += b2f(v.w);
            }

            acc.x += __shfl_xor(acc.x, 32);
            acc.y += __shfl_xor(acc.y, 32);
            acc.z += __shfl_xor(acc.z, 32);
            acc.w += __shfl_xor(acc.w, 32);
            if (half == 0) {
                ushort4 o = {f2b(acc.x), f2b(acc.y), f2b(acc.z), f2b(acc.w)};
                *reinterpret_cast<ushort4*>(&a_lds[n][c4]) = o;
            }
        } else if (half == 0) {
            ushort4 zz = {0, 0, 0, 0};
            *reinterpret_cast<ushort4*>(&a_lds[n][c4]) = zz;   // keep MFMA clean
        }
    }
    __syncthreads();

    const int mbase = (wv >> 2) * 32;   // 0 or 32
    const int nbase = (wv & 3) * 32;    // 0,32,64,96

    // ---- phase 3: t = relu(a @ Wa + ba) ----
    f32x4 acc[2][2];
#pragma unroll
    for (int m = 0; m < 2; ++m)
#pragma unroll
        for (int nf = 0; nf < 2; ++nf) acc[m][nf] = (f32x4){0.f, 0.f, 0.f, 0.f};

#pragma unroll
    for (int k0 = 0; k0 < 4; ++k0) {
        const int kk = k0 * 32 + g * 8;
        bf16x8 a0 = *reinterpret_cast<const bf16x8*>(&a_lds[mbase + l16][kk]);
        bf16x8 a1 = *reinterpret_cast<const bf16x8*>(&a_lds[mbase + 16 + l16][kk]);
#pragma unroll
        for (int nf = 0; nf < 2; ++nf) {
            bf16x8 bb = *reinterpret_cast<const bf16x8*>(
                WTa + (size_t)(nbase + nf * 16 + l16) * FD + kk);
            acc[0][nf] = __builtin_amdgcn_mfma_f32_16x16x32_bf16(a0, bb, acc[0][nf], 0, 0, 0);
            acc[1][nf] = __builtin_amdgcn_mfma_f32_16x16x32_bf16(a1, bb, acc[1][nf], 0, 0, 0);
        }
    }

#pragma unroll
    for (int m = 0; m < 2; ++m) {
#pragma unroll
        for (int nf = 0; nf < 2; ++nf) {
            int col = nbase + nf * 16 + l16;
            float bc = biasa[col];
#pragma unroll
            for (int r = 0; r < 4; ++r) {
                int row = mbase + 16 * m + g * 4 + r;
                t_lds[row][col] = f2b(fmaxf(acc[m][nf][r] + bc, 0.f));
            }
        }
    }
    __syncthreads();

    // ---- phase 4: out = relu(t @ Wb + bb) ----
    f32x4 acc2[2][2];
#pragma unroll
    for (int m = 0; m < 2; ++m)
#pragma unroll
        for (int nf = 0; nf < 2; ++nf) acc2[m][nf] = (f32x4){0.f, 0.f, 0.f, 0.f};

#pragma unroll
    for (int k0 = 0; k0 < 4; ++k0) {
        const int kk = k0 * 32 + g * 8;
        bf16x8 a0 = *reinterpret_cast<const bf16x8*>(&t_lds[mbase + l16][kk]);
        bf16x8 a1 = *reinterpret_cast<const bf16x8*>(&t_lds[mbase + 16 + l16][kk]);
#pragma unroll
        for (int nf = 0; nf < 2; ++nf) {
            bf16x8 bb = *reinterpret_cast<const bf16x8*>(
                WTb + (size_t)(nbase + nf * 16 + l16) * FD + kk);
            acc2[0][nf] = __builtin_amdgcn_mfma_f32_16x16x32_bf16(a0, bb, acc2[0][nf], 0, 0, 0);
            acc2[1][nf] = __builtin_amdgcn_mfma_f32_16x16x32_bf16(a1, bb, acc2[1][nf], 0, 0, 0);
        }
    }

#pragma unroll
    for (int m = 0; m < 2; ++m) {
#pragma unroll
        for (int nf = 0; nf < 2; ++nf) {
            int col = nbase + nf * 16 + l16;
            float bc = biasb[col];
#pragma unroll
            for (int r = 0; r < 4; ++r) {
                int row = node0 + mbase + 16 * m + g * 4 + r;
                if (row < NN) {
                    float v = fmaxf(acc2[m][nf][r] + bc, 0.f);
                    if (F32OUT)
                        reinterpret_cast<float*>(outv)[(size_t)row * FD + col] = v;
                    else
                        reinterpret_cast<u16*>(outv)[(size_t)row * FD + col] = f2b(v);
                }
            }
        }
    }
}

extern "C" void kernel_launch(void* const* d_in, const int* in_sizes, int n_in,
                              void* d_out, int out_size, void* d_ws, size_t ws_size,
                              hipStream_t stream) {
    const float* x   = (const float*)d_in[0];
    const int*   ei  = (const int*)d_in[1];
    const float* W1a = (const float*)d_in[2];
    const float* b1a = (const float*)d_in[3];
    const float* W1b = (const float*)d_in[4];
    const float* b1b = (const float*)d_in[5];
    const float* W2a = (const float*)d_in[6];
    const float* b2a = (const float*)d_in[7];
    const float* W2b = (const float*)d_in[8];
    const float* b2b = (const float*)d_in[9];

    const size_t feat = (size_t)NN * FD;
    u16* xb = (u16*)d_ws;             // 12.8 MB (x bf16)
    u16* zb = xb + feat;              // 12.8 MB (h1 bf16)
    u16* wt = zb + feat;              // 128 KB
    int* gcnt = (int*)(wt + 4 * FD * FD);       // 1024 ints
    u32* ebuf = (u32*)(gcnt + 1024);            // NB*BCAP*4 = 4.80 MB
    u16* sbuf = (u16*)(ebuf + (size_t)NB * BCAP); // NB*BCAP*2 = 2.40 MB
    int* noff = (int*)(sbuf + (size_t)NB * BCAP); // NB*65*4 = 204 KB

    const int cBlocks = (int)(feat / (256 * 8));// 3125

    convert_x_kernel<<<cBlocks, 256, 0, stream>>>(x, xb);
    convert_w_kernel<<<4, 256, 0, stream>>>(W1a, W1b, W2a, W2b, wt);

    hipMemsetAsync(gcnt, 0, NB * sizeof(int), stream);
    bin_kernel<<<NWG_BIN, 256, 0, stream>>>(ei, ebuf, gcnt);
    sort_kernel<<<NB, 256, 0, stream>>>(ebuf, gcnt, sbuf, noff);

    // conv1: xb -> zb (bf16)
    conv_kernel<false><<<NB, 512, 0, stream>>>(
        xb, sbuf, noff, wt, b1a, wt + 1 * FD * FD, b1b, zb);
    // conv2: zb -> d_out (fp32)
    conv_kernel<true><<<NB, 512, 0, stream>>>(
        zb, sbuf, noff, wt + 2 * FD * FD, b2a, wt + 3 * FD * FD, b2b, (float*)d_out);
}

// Round 8
// 132.759 us; speedup vs baseline: 8.7742x; 1.0264x over previous
//
#include <hip/hip_runtime.h>

// GIN: 2x GINConv(eps=0), N=50000, E=800000, d=128. bf16 + MFMA.
// R8: gather restructured — each 16-lane group owns one node (4 nodes/wave),
// dwordx4 row reads (16B/lane), float-bit bf16 unpack (u<<16 / u&0xFFFF0000),
// 2x unroll, no cross-lane reduce. conv1 bf16 output staged through t_lds for
// coalesced full-line stores (was 2x write-amplified scalar u16 stores).
// ws: [ xb 12.8M | zb 12.8M | wt 128K | gcnt 4K | ebuf 4.8M | sbuf 2.4M | noff 204K ]

#define NN 50000
#define NE 800000
#define FD 128
#define BNODES 64
#define NB 782           // ceil(NN/64); bucket 781 has 16 nodes
#define BCAP 1536        // max edges/bucket: mean 1024, sigma 32 -> +16 sigma
#define EPW 4096
#define NWG_BIN 196      // ceil(NE/EPW)

typedef unsigned short u16;
typedef unsigned int u32;
typedef __attribute__((ext_vector_type(8))) short bf16x8;
typedef __attribute__((ext_vector_type(4))) float f32x4;

static __device__ __forceinline__ float b2f(u16 u) {
    return __uint_as_float(((u32)u) << 16);
}
static __device__ __forceinline__ u16 f2b(float f) {
    u32 x = __float_as_uint(f);
    u32 r = x + 0x7FFFu + ((x >> 16) & 1u);   // RNE
    return (u16)(r >> 16);
}

// unpack-accumulate a uint4 (8 bf16) into acc0/acc1 via exact float-bit tricks
#define ACCUM(v) do { \
    acc0.x += __uint_as_float((v).x << 16); \
    acc0.y += __uint_as_float((v).x & 0xFFFF0000u); \
    acc0.z += __uint_as_float((v).y << 16); \
    acc0.w += __uint_as_float((v).y & 0xFFFF0000u); \
    acc1.x += __uint_as_float((v).z << 16); \
    acc1.y += __uint_as_float((v).z & 0xFFFF0000u); \
    acc1.z += __uint_as_float((v).w << 16); \
    acc1.w += __uint_as_float((v).w & 0xFFFF0000u); } while (0)

// ---------------- converts ----------------

__global__ __launch_bounds__(256) void convert_x_kernel(
    const float* __restrict__ x, u16* __restrict__ xb)
{
    int gid = blockIdx.x * 256 + threadIdx.x;
    size_t base = (size_t)gid * 8;
    float4 a = *reinterpret_cast<const float4*>(x + base);
    float4 b = *reinterpret_cast<const float4*>(x + base + 4);
    u32 w0 = (u32)f2b(a.x) | ((u32)f2b(a.y) << 16);
    u32 w1 = (u32)f2b(a.z) | ((u32)f2b(a.w) << 16);
    u32 w2 = (u32)f2b(b.x) | ((u32)f2b(b.y) << 16);
    u32 w3 = (u32)f2b(b.z) | ((u32)f2b(b.w) << 16);
    uint4 o = {w0, w1, w2, w3};
    *reinterpret_cast<uint4*>(xb + base) = o;
}

// W [128][128] fp32 row-major -> WT[n][k] = W[k][n] bf16
__global__ __launch_bounds__(256) void convert_w_kernel(
    const float* __restrict__ w0, const float* __restrict__ w1,
    const float* __restrict__ w2, const float* __restrict__ w3,
    u16* __restrict__ wt)
{
    int b = blockIdx.x;
    const float* W = (b == 0) ? w0 : (b == 1) ? w1 : (b == 2) ? w2 : w3;
    u16* out = wt + (size_t)b * FD * FD;
    for (int idx = threadIdx.x; idx < FD * FD; idx += 256) {
        int n = idx >> 7, k = idx & 127;
        out[idx] = f2b(W[k * FD + n]);
    }
}

// ---------------- bucket binning ----------------
// Edges grouped by bucket b = dst>>6 into ebuf[b*BCAP ...], packed
// u32 = src | (dst_local << 16).

__global__ __launch_bounds__(256) void bin_kernel(
    const int* __restrict__ ei, u32* __restrict__ ebuf, int* __restrict__ gcnt)
{
    __shared__ int cnt[1024];
    __shared__ int lofs[1024];
    __shared__ int cur[1024];
    __shared__ int gb[1024];
    __shared__ int csum[16];
    __shared__ int cofs[16];
    __shared__ u32 vals[EPW];
    __shared__ u16 bkt[EPW];

    const int tid = threadIdx.x, lane = tid & 63, wv = tid >> 6;
    const int e0 = blockIdx.x * EPW;
    const int nE = min(EPW, NE - e0);
    const int* dstp = ei + NE;

    for (int i = tid; i < 1024; i += 256) { cnt[i] = 0; cur[i] = 0; }
    __syncthreads();

    for (int k = 0; k < EPW / 256; ++k) {
        int e = e0 + k * 256 + tid;
        if (e < NE) atomicAdd(&cnt[(u32)dstp[e] >> 6], 1);
    }
    __syncthreads();

    // exclusive scan over 1024 slots (16 chunks of 64)
    for (int cc = 0; cc < 4; ++cc) {
        int c = wv + cc * 4;
        int i = c * 64 + lane;
        int v = cnt[i];
        int sc = v;
#pragma unroll
        for (int s = 1; s < 64; s <<= 1) {
            int t = __shfl_up(sc, s);
            if (lane >= s) sc += t;
        }
        lofs[i] = sc - v;
        if (lane == 63) csum[c] = sc;
    }
    __syncthreads();
    if (wv == 0) {
        int s = (lane < 16) ? csum[lane] : 0;
        int sc = s;
#pragma unroll
        for (int st = 1; st < 16; st <<= 1) {
            int u = __shfl_up(sc, st);
            if (lane >= st) sc += u;
        }
        if (lane < 16) cofs[lane] = sc - s;
    }
    __syncthreads();
    for (int cc = 0; cc < 4; ++cc) {
        int c = wv + cc * 4;
        lofs[c * 64 + lane] += cofs[c];
    }
    __syncthreads();

    // place (bucket-grouped in LDS)
    for (int k = 0; k < EPW / 256; ++k) {
        int e = e0 + k * 256 + tid;
        if (e < NE) {
            int s = ei[e];
            u32 d = (u32)dstp[e];
            int b = d >> 6;
            int p = lofs[b] + atomicAdd(&cur[b], 1);
            vals[p] = (u32)s | ((d & 63u) << 16);
            bkt[p] = (u16)b;
        }
    }
    __syncthreads();

    // claim global chunks
    for (int b = tid; b < NB; b += 256) {
        int c = cur[b];
        gb[b] = c ? atomicAdd(&gcnt[b], c) : 0;
    }
    __syncthreads();

    // flush bucket-grouped -> contiguous runs
    for (int idx = tid; idx < nE; idx += 256) {
        int b = bkt[idx];
        ebuf[(size_t)b * BCAP + gb[b] + (idx - lofs[b])] = vals[idx];
    }
}

// ---------------- one-time counting sort per bucket ----------------
// ebuf (packed, unordered) -> sbuf (u16 src, grouped by dst_local) + noff.

__global__ __launch_bounds__(256) void sort_kernel(
    const u32* __restrict__ ebuf, const int* __restrict__ gcnt,
    u16* __restrict__ sbuf, int* __restrict__ noff)
{
    __shared__ u32 stage[BCAP];    // 6 KB
    __shared__ u16 sorted[BCAP];   // 3 KB
    __shared__ int cnt64[64];
    __shared__ int off64[65];
    __shared__ int cur64[64];

    const int tid = threadIdx.x, lane = tid & 63, wv = tid >> 6;
    const int b = blockIdx.x;
    const int cnt = gcnt[b];
    const u32* eb = ebuf + (size_t)b * BCAP;

    if (tid < 64) cnt64[tid] = 0;
    __syncthreads();

    for (int e = tid; e < cnt; e += 256) {
        u32 v = eb[e];
        stage[e] = v;
        atomicAdd(&cnt64[v >> 16], 1);
    }
    __syncthreads();

    if (wv == 0) {
        int v = cnt64[lane];
        int sc = v;
#pragma unroll
        for (int s = 1; s < 64; s <<= 1) {
            int t = __shfl_up(sc, s);
            if (lane >= s) sc += t;
        }
        off64[lane + 1] = sc;
        cur64[lane] = sc - v;
        if (lane == 0) off64[0] = 0;
    }
    __syncthreads();

    for (int e = tid; e < cnt; e += 256) {
        u32 v = stage[e];
        int pos = atomicAdd(&cur64[v >> 16], 1);
        sorted[pos] = (u16)(v & 0xFFFFu);   // src < 50000 fits u16
    }
    __syncthreads();

    if (tid < 65) noff[b * 65 + tid] = off64[tid];
    u32* sb = (u32*)(sbuf + (size_t)b * BCAP);
    const u32* so = (const u32*)sorted;
    for (int i = tid; i * 2 < cnt; i += 256) sb[i] = so[i];
}

// ---------------- fused conv: gather -> a_lds -> MLP (2 MFMA GEMMs) --------
// Block = bucket = M-tile (64 nodes). 8 waves.
// Gather: 16-lane group per node (4 nodes/wave), dwordx4 row reads, float-bit
// bf16 unpack, f32 register accum, no cross-lane reduce.
// GEMM: 8 waves as 2Mx4N; weights read as B-frags from global (L2-resident).
// k-map phi(g,i)=8g+i both operands; D: col=lane&15, row=(lane>>4)*4+reg.

template <bool F32OUT>
__global__ __launch_bounds__(512, 6) void conv_kernel(
    const u16* __restrict__ h, const u16* __restrict__ sbuf,
    const int* __restrict__ noff,
    const u16* __restrict__ WTa, const float* __restrict__ biasa,
    const u16* __restrict__ WTb, const float* __restrict__ biasb,
    void* __restrict__ outv)
{
    __shared__ u16 a_lds[64][136];   // 17.4 KB
    __shared__ u16 t_lds[64][136];   // 17.4 KB
    __shared__ u16 sorted[BCAP];     // 3 KB
    __shared__ int off[65];

    const int tid = threadIdx.x;
    const int lane = tid & 63;
    const int wv = tid >> 6;         // 0..7
    const int b = blockIdx.x;
    const int node0 = b * BNODES;
    const int nNodes = min(BNODES, NN - node0);
    const int g = lane >> 4;         // group 0..3
    const int l16 = lane & 15;

    // ---- phase 1: load sorted edge list + offsets ----
    if (tid < 65) off[tid] = noff[b * 65 + tid];
    __syncthreads();
    const int cnt = off[64];
    {
        const u32* sb = (const u32*)(sbuf + (size_t)b * BCAP);
        u32* so = (u32*)sorted;
        for (int i = tid; i * 2 < cnt; i += 512) so[i] = sb[i];
    }
    __syncthreads();

    // ---- phase 2: gather into a_lds (group g handles node q*4+g) ----
    const u16* hcol = h + l16 * 8;   // this lane's 8-feature column slice

    for (int q = wv; q < 16; q += 8) {
        const int n = q * 4 + g;
        float4 acc0 = {0.f, 0.f, 0.f, 0.f};
        float4 acc1 = {0.f, 0.f, 0.f, 0.f};
        if (n < nNodes) {
            uint4 v = *reinterpret_cast<const uint4*>(hcol + (size_t)(node0 + n) * FD);
            ACCUM(v);   // self term
            int e = off[n];
            const int end = off[n + 1];
            for (; e + 1 < end; e += 2) {
                int s0 = sorted[e];
                int s1 = sorted[e + 1];
                uint4 v0 = *reinterpret_cast<const uint4*>(hcol + (size_t)s0 * FD);
                uint4 v1 = *reinterpret_cast<const uint4*>(hcol + (size_t)s1 * FD);
                ACCUM(v0);
                ACCUM(v1);
            }
            if (e < end) {
                int s0 = sorted[e];
                uint4 v0 = *reinterpret_cast<const uint4*>(hcol + (size_t)s0 * FD);
                ACCUM(v0);
            }
        }
        uint4 o;
        o.x = (u32)f2b(acc0.x) | ((u32)f2b(acc0.y) << 16);
        o.y = (u32)f2b(acc0.z) | ((u32)f2b(acc0.w) << 16);
        o.z = (u32)f2b(acc1.x) | ((u32)f2b(acc1.y) << 16);
        o.w = (u32)f2b(acc1.z) | ((u32)f2b(acc1.w) << 16);
        *reinterpret_cast<uint4*>(&a_lds[n][l16 * 8]) = o;   // zeros for pad rows
    }
    __syncthreads();

    const int mbase = (wv >> 2) * 32;   // 0 or 32
    const int nbase = (wv & 3) * 32;    // 0,32,64,96

    // ---- phase 3: t = relu(a @ Wa + ba) ----
    f32x4 acc[2][2];
#pragma unroll
    for (int m = 0; m < 2; ++m)
#pragma unroll
        for (int nf = 0; nf < 2; ++nf) acc[m][nf] = (f32x4){0.f, 0.f, 0.f, 0.f};

#pragma unroll
    for (int k0 = 0; k0 < 4; ++k0) {
        const int kk = k0 * 32 + g * 8;
        bf16x8 a0 = *reinterpret_cast<const bf16x8*>(&a_lds[mbase + l16][kk]);
        bf16x8 a1 = *reinterpret_cast<const bf16x8*>(&a_lds[mbase + 16 + l16][kk]);
#pragma unroll
        for (int nf = 0; nf < 2; ++nf) {
            bf16x8 bb = *reinterpret_cast<const bf16x8*>(
                WTa + (size_t)(nbase + nf * 16 + l16) * FD + kk);
            acc[0][nf] = __builtin_amdgcn_mfma_f32_16x16x32_bf16(a0, bb, acc[0][nf], 0, 0, 0);
            acc[1][nf] = __builtin_amdgcn_mfma_f32_16x16x32_bf16(a1, bb, acc[1][nf], 0, 0, 0);
        }
    }

#pragma unroll
    for (int m = 0; m < 2; ++m) {
#pragma unroll
        for (int nf = 0; nf < 2; ++nf) {
            int col = nbase + nf * 16 + l16;
            float bc = biasa[col];
#pragma unroll
            for (int r = 0; r < 4; ++r) {
                int row = mbase + 16 * m + g * 4 + r;
                t_lds[row][col] = f2b(fmaxf(acc[m][nf][r] + bc, 0.f));
            }
        }
    }
    __syncthreads();

    // ---- phase 4: out = relu(t @ Wb + bb) ----
    f32x4 acc2[2][2];
#pragma unroll
    for (int m = 0; m < 2; ++m)
#pragma unroll
        for (int nf = 0; nf < 2; ++nf) acc2[m][nf] = (f32x4){0.f, 0.f, 0.f, 0.f};

#pragma unroll
    for (int k0 = 0; k0 < 4; ++k0) {
        const int kk = k0 * 32 + g * 8;
        bf16x8 a0 = *reinterpret_cast<const bf16x8*>(&t_lds[mbase + l16][kk]);
        bf16x8 a1 = *reinterpret_cast<const bf16x8*>(&t_lds[mbase + 16 + l16][kk]);
#pragma unroll
        for (int nf = 0; nf < 2; ++nf) {
            bf16x8 bb = *reinterpret_cast<const bf16x8*>(
                WTb + (size_t)(nbase + nf * 16 + l16) * FD + kk);
            acc2[0][nf] = __builtin_amdgcn_mfma_f32_16x16x32_bf16(a0, bb, acc2[0][nf], 0, 0, 0);
            acc2[1][nf] = __builtin_amdgcn_mfma_f32_16x16x32_bf16(a1, bb, acc2[1][nf], 0, 0, 0);
        }
    }

    if (F32OUT) {
        // f32 frag stores are already full-line (16 consecutive f32 = 64B)
#pragma unroll
        for (int m = 0; m < 2; ++m) {
#pragma unroll
            for (int nf = 0; nf < 2; ++nf) {
                int col = nbase + nf * 16 + l16;
                float bc = biasb[col];
#pragma unroll
                for (int r = 0; r < 4; ++r) {
                    int row = node0 + mbase + 16 * m + g * 4 + r;
                    if (row < NN) {
                        float v = fmaxf(acc2[m][nf][r] + bc, 0.f);
                        reinterpret_cast<float*>(outv)[(size_t)row * FD + col] = v;
                    }
                }
            }
        }
    } else {
        // stage bf16 result in t_lds (free after phase 4 reads), then
        // coalesced 16B/lane copy-out — avoids 2x partial-line writebacks.
        __syncthreads();
#pragma unroll
        for (int m = 0; m < 2; ++m) {
#pragma unroll
            for (int nf = 0; nf < 2; ++nf) {
                int col = nbase + nf * 16 + l16;
                float bc = biasb[col];
#pragma unroll
                for (int r = 0; r < 4; ++r) {
                    int row = mbase + 16 * m + g * 4 + r;
                    t_lds[row][col] = f2b(fmaxf(acc2[m][nf][r] + bc, 0.f));
                }
            }
        }
        __syncthreads();
        u16* outp = reinterpret_cast<u16*>(outv);
#pragma unroll
        for (int it = 0; it < 2; ++it) {
            int idx = tid + it * 512;
            int r = idx >> 4, c = (idx & 15) * 8;
            if (node0 + r < NN)
                *reinterpret_cast<uint4*>(outp + (size_t)(node0 + r) * FD + c) =
                    *reinterpret_cast<const uint4*>(&t_lds[r][c]);
        }
    }
}

extern "C" void kernel_launch(void* const* d_in, const int* in_sizes, int n_in,
                              void* d_out, int out_size, void* d_ws, size_t ws_size,
                              hipStream_t stream) {
    const float* x   = (const float*)d_in[0];
    const int*   ei  = (const int*)d_in[1];
    const float* W1a = (const float*)d_in[2];
    const float* b1a = (const float*)d_in[3];
    const float* W1b = (const float*)d_in[4];
    const float* b1b = (const float*)d_in[5];
    const float* W2a = (const float*)d_in[6];
    const float* b2a = (const float*)d_in[7];
    const float* W2b = (const float*)d_in[8];
    const float* b2b = (const float*)d_in[9];

    const size_t feat = (size_t)NN * FD;
    u16* xb = (u16*)d_ws;             // 12.8 MB (x bf16)
    u16* zb = xb + feat;              // 12.8 MB (h1 bf16)
    u16* wt = zb + feat;              // 128 KB
    int* gcnt = (int*)(wt + 4 * FD * FD);       // 1024 ints
    u32* ebuf = (u32*)(gcnt + 1024);            // NB*BCAP*4 = 4.80 MB
    u16* sbuf = (u16*)(ebuf + (size_t)NB * BCAP); // NB*BCAP*2 = 2.40 MB
    int* noff = (int*)(sbuf + (size_t)NB * BCAP); // NB*65*4 = 204 KB

    const int cBlocks = (int)(feat / (256 * 8));// 3125

    convert_x_kernel<<<cBlocks, 256, 0, stream>>>(x, xb);
    convert_w_kernel<<<4, 256, 0, stream>>>(W1a, W1b, W2a, W2b, wt);

    hipMemsetAsync(gcnt, 0, NB * sizeof(int), stream);
    bin_kernel<<<NWG_BIN, 256, 0, stream>>>(ei, ebuf, gcnt);
    sort_kernel<<<NB, 256, 0, stream>>>(ebuf, gcnt, sbuf, noff);

    // conv1: xb -> zb (bf16)
    conv_kernel<false><<<NB, 512, 0, stream>>>(
        xb, sbuf, noff, wt, b1a, wt + 1 * FD * FD, b1b, zb);
    // conv2: zb -> d_out (fp32)
    conv_kernel<true><<<NB, 512, 0, stream>>>(
        zb, sbuf, noff, wt + 2 * FD * FD, b2a, wt + 3 * FD * FD, b2b, (float*)d_out);
}